// Round 11
// baseline (49.084 us; speedup 1.0000x reference)
//
#include <hip/hip_runtime.h>

#define B_ 16
#define A_ 3
#define G_ 76
#define GG_ (G_*G_)             // 5776
#define NC_ 80
#define C_ 85
#define NCELL (B_*A_*GG_)       // 277248
#define OUTN ((size_t)NCELL*C_) // 23566080
#define NBLKM (NCELL/64)        // 4332 blocks, 64 cells each
#define NSLOT (C_*16)           // 1360 f4 slots per block (85 channels x 16 quads)

typedef float f4 __attribute__((ext_vector_type(4)));

__device__ __forceinline__ float sigf(float v){ return 1.0f/(1.0f + __expf(-v)); }
__device__ __forceinline__ float clog_(float p){ return fmaxf(__logf(p), -100.0f); }
__device__ __forceinline__ float bcef(float p, float t){ return -(t*clog_(p) + (1.0f-t)*clog_(1.0f-p)); }

// ---------------- mega: block-cooperative quad transpose + transform + fused loss ----------
// Block = 64 cells. Phase A slot idx in [0,1360): k = idx>>4 (channel), q = idx&15 (cell quad).
// Since GG_%4==0 and G_%4==0, a 4-aligned cell quad stays in one (b,a) plane and one row.
__global__ __launch_bounds__(256, 6) void mega_kernel(
        const float* __restrict__ x, const float* __restrict__ iou,
        const unsigned int* __restrict__ om, const unsigned int* __restrict__ nm,
        const float* __restrict__ tw, const float* __restrict__ th,
        const float* __restrict__ tcls, const float* __restrict__ tconf,
        const float* __restrict__ tbox,
        float* __restrict__ out, float* __restrict__ partials){
    __shared__ __align__(16) float lds[64*C_];   // transformed tile [cell][channel], 21760 B
    __shared__ float praw[64][2];                // raw pw, ph per cell
    __shared__ float sred[4][6];

    const int tid  = (int)threadIdx.x;
    const int w    = tid >> 6;
    const int lane = tid & 63;

    // bijective XCD-chunked swizzle (NBLKM % 8 == 4)
    unsigned qd8 = NBLKM >> 3, rr = NBLKM & 7u;
    unsigned xcd = blockIdx.x & 7u, seq = blockIdx.x >> 3;
    int blk = (int)((xcd < rr ? xcd*(qd8+1u) : rr*(qd8+1u) + (xcd-rr)*qd8) + seq);
    int n0 = blk*64;

    // ---- phase A1: stage 6 cooperative f4 loads (1 KB per wave-instruction) ----
    f4 rv[6];
    #pragma unroll
    for (int it=0; it<6; ++it){
        int idx = tid + it*256;
        if (idx < NSLOT){
            int k = idx >> 4, q = idx & 15;
            int cell0 = n0 + 4*q;
            int ba = cell0 / GG_;
            int ij0 = cell0 - ba*GG_;
            rv[it] = *(const f4*)(x + ((size_t)ba*C_ + (size_t)k)*GG_ + ij0);
        }
    }

    // ---- phase A2: transform (lane-uniform k) + transposed scalar ds_writes ----
    #pragma unroll
    for (int it=0; it<6; ++it){
        int idx = tid + it*256;
        if (idx < NSLOT){
            int k = idx >> 4, q = idx & 15;
            int cell0 = n0 + 4*q;
            int ba = cell0 / GG_;
            int ij0 = cell0 - ba*GG_;
            int in_ = ij0 / G_;
            int jn0 = ij0 - in_*G_;
            int a = ba % A_;
            int lc0 = 4*q;
            f4 v = rv[it];
            f4 r;
            if (k >= 4){
                r[0]=sigf(v[0]); r[1]=sigf(v[1]); r[2]=sigf(v[2]); r[3]=sigf(v[3]);
            } else if (k == 0){
                float j0 = (float)jn0;
                r[0]=(sigf(v[0])+j0)*8.0f;      r[1]=(sigf(v[1])+j0+1.0f)*8.0f;
                r[2]=(sigf(v[2])+j0+2.0f)*8.0f; r[3]=(sigf(v[3])+j0+3.0f)*8.0f;
            } else if (k == 1){
                float fi = (float)in_;
                r[0]=(sigf(v[0])+fi)*8.0f; r[1]=(sigf(v[1])+fi)*8.0f;
                r[2]=(sigf(v[2])+fi)*8.0f; r[3]=(sigf(v[3])+fi)*8.0f;
            } else if (k == 2){
                float aw8 = (a==0)?12.0f:((a==1)?19.0f:40.0f);
                r[0]=__expf(v[0])*aw8; r[1]=__expf(v[1])*aw8;
                r[2]=__expf(v[2])*aw8; r[3]=__expf(v[3])*aw8;
                praw[lc0+0][0]=v[0]; praw[lc0+1][0]=v[1];
                praw[lc0+2][0]=v[2]; praw[lc0+3][0]=v[3];
            } else { // k == 3
                float ah8 = (a==0)?16.0f:((a==1)?36.0f:28.0f);
                r[0]=__expf(v[0])*ah8; r[1]=__expf(v[1])*ah8;
                r[2]=__expf(v[2])*ah8; r[3]=__expf(v[3])*ah8;
                praw[lc0+0][1]=v[0]; praw[lc0+1][1]=v[1];
                praw[lc0+2][1]=v[2]; praw[lc0+3][1]=v[3];
            }
            int bix = lc0*C_ + k;            // banks: (20q + k) mod 32 -> exact 2-way (free)
            lds[bix]       = r[0];
            lds[bix+C_]    = r[1];
            lds[bix+2*C_]  = r[2];
            lds[bix+3*C_]  = r[3];
        }
    }
    __syncthreads();

    // ---- phase B: contiguous f4 copy-out (fully coalesced) ----
    {
        const f4* src4 = (const f4*)lds;
        f4* dst4 = (f4*)(out + (size_t)n0*C_);
        #pragma unroll
        for (int it=0; it<6; ++it){
            int f = tid + it*256;
            if (f < NSLOT) dst4[f] = src4[f];
        }
    }

    // ---- loss: 4 threads per cell (qd splits 80 classes); qd0=CIoU, qd1=conf ----
    int lc = tid >> 2, qd = tid & 3;
    int n  = n0 + lc;
    bool obj   = om[n] != 0u;     // 4-byte elements: int32 {0,1} or f32 {0,1.0f}
    bool noobj = nm[n] != 0u;
    const float* lrow = lds + lc*C_;

    float cls = 0.f;
    if (obj){
        const float* tcl = tcls + (size_t)n*NC_ + qd*20;
        const float* lp  = lrow + 5 + qd*20;
        #pragma unroll 4
        for (int j=0; j<20; ++j) cls += bcef(lp[j], tcl[j]);
    }
    cls += __shfl_xor(cls, 1, 64);
    cls += __shfl_xor(cls, 2, 64);
    if (qd != 0) cls = 0.f;

    float ciou=0.f, co=0.f, cn=0.f;
    if (qd == 0 && obj){
        float bx = lrow[0]*0.125f, by = lrow[1]*0.125f;
        float bw = lrow[2]*0.125f, bh = lrow[3]*0.125f;
        float rwv = praw[lc][0], rhv = praw[lc][1];
        float iouv = iou[n], twv = tw[n], thv = th[n];
        f4 tb = *(const f4*)(tbox + (size_t)n*4);
        float txc=tb[0], tyc=tb[1], twd=tb[2], tht=tb[3];
        float tx1 = txc - twd*0.5f, ty1 = tyc - tht*0.5f;
        float tx2 = txc + twd*0.5f, ty2 = tyc + tht*0.5f;
        float px1 = bx - bw*0.5f,  py1 = by - bh*0.5f;
        float px2 = bx + bw*0.5f,  py2 = by + bh*0.5f;
        float xc1 = fminf(px1, tx1), yc1 = fminf(py1, ty1);
        float xc2 = fmaxf(px2, tx2), yc2 = fmaxf(py2, ty2);
        float cc = (xc2-xc1)*(xc2-xc1) + (yc2-yc1)*(yc2-yc1) + 1e-7f;
        float dd = (txc-bx)*(txc-bx) + (tyc-by)*(tyc-by);
        float rdiou = dd/cc;
        float dat = atanf(twv/thv) - atanf(rwv/rhv);
        float vv = 0.40528473456935108577f * dat*dat;
        float Si = 1.0f - iouv;
        float alpha = vv/(Si+vv);
        ciou = 1.0f - iouv + rdiou + alpha*vv;
    }
    if (qd == 1 && (obj || noobj)){
        float bc = bcef(lrow[4], tconf[n]);
        co = obj ? bc : 0.f;
        cn = noobj ? bc : 0.f;
    }
    unsigned long long bo  = __ballot(obj   && qd == 0);   // one lane per cell
    unsigned long long bn2 = __ballot(noobj && qd == 1);

    float vals[4] = {ciou, co, cn, cls};
    #pragma unroll
    for (int q2=0; q2<4; ++q2){
        float v = vals[q2];
        #pragma unroll
        for (int o=32; o>0; o>>=1) v += __shfl_xor(v, o, 64);
        vals[q2] = v;
    }
    if (lane == 0){
        sred[w][0]=vals[0]; sred[w][1]=vals[1]; sred[w][2]=vals[2]; sred[w][3]=vals[3];
        sred[w][4]=(float)__popcll(bo); sred[w][5]=(float)__popcll(bn2);
    }
    __syncthreads();
    if (tid < 6)
        partials[(size_t)tid*NBLKM + blk] = sred[0][tid]+sred[1][tid]+sred[2][tid]+sred[3][tid];
}

// ---------------- final reduction ----------------
__global__ __launch_bounds__(256) void final_kernel(const float* __restrict__ partials,
                                                    float* __restrict__ out_loss){
    double acc[6] = {0,0,0,0,0,0};
    for (int idx = (int)threadIdx.x; idx < NBLKM; idx += 256){
        #pragma unroll
        for (int q=0;q<6;q++) acc[q] += (double)partials[(size_t)q*NBLKM + idx];
    }
    #pragma unroll
    for (int q=0;q<6;q++){
        double v = acc[q];
        #pragma unroll
        for (int o=32;o>0;o>>=1) v += __shfl_xor(v, o, 64);
        acc[q] = v;
    }
    __shared__ double smd[6][4];
    int lane = (int)threadIdx.x & 63, wid = (int)threadIdx.x >> 6;
    if (lane == 0){
        #pragma unroll
        for (int q=0;q<6;q++) smd[q][wid] = acc[q];
    }
    __syncthreads();
    if (threadIdx.x == 0){
        double s[6];
        #pragma unroll
        for (int q=0;q<6;q++) s[q] = smd[q][0]+smd[q][1]+smd[q][2]+smd[q][3];
        double cnt_o = fmax(s[4], 1.0);
        double cnt_n = fmax(s[5], 1.0);
        double total = s[0]/(double)B_
                     + s[1]/cnt_o
                     + 100.0*s[2]/cnt_n
                     + s[3]/(cnt_o*(double)NC_);
        *out_loss = (float)total;
    }
}

extern "C" void kernel_launch(void* const* d_in, const int* in_sizes, int n_in,
                              void* d_out, int out_size, void* d_ws, size_t ws_size,
                              hipStream_t stream){
    const float* x     = (const float*)d_in[0];
    const float* iou   = (const float*)d_in[1];
    const unsigned int* om = (const unsigned int*)d_in[2];
    const unsigned int* nm = (const unsigned int*)d_in[3];
    const float* tw    = (const float*)d_in[4];
    const float* th    = (const float*)d_in[5];
    const float* tcls  = (const float*)d_in[6];
    const float* tconf = (const float*)d_in[7];
    const float* tbox  = (const float*)d_in[8];
    float* out = (float*)d_out;

    float* partials = (float*)d_ws;

    mega_kernel<<<NBLKM, 256, 0, stream>>>(x, iou, om, nm, tw, th, tcls, tconf, tbox,
                                           out, partials);
    final_kernel<<<1, 256, 0, stream>>>(partials, out + OUTN);
}